// Round 1
// baseline (1206.269 us; speedup 1.0000x reference)
//
#include <hip/hip_runtime.h>

#define HEADS 4
#define OUT_C 32
#define HC 128        // HEADS*OUT_C
#define NEG_SLOPE 0.2f
#define EPS 1e-16f

// -------- K1: h = x @ W   (N x 128) = (N x 128)(128 x 128), fp32 vector ALU --------
// block = 256 threads, tile = 16 rows x 128 cols; each thread computes 8 outputs.
__global__ __launch_bounds__(256) void gemm_xw(const float* __restrict__ x,
                                               const float* __restrict__ W,
                                               float* __restrict__ h, int N) {
    __shared__ float xs[16 * 128];   // 8 KB
    const int tid  = threadIdx.x;
    const int row0 = blockIdx.x * 16;
    // stage x tile (coalesced)
    for (int i = tid; i < 16 * 128; i += 256) {
        int r = row0 + (i >> 7);
        xs[i] = (r < N) ? x[(size_t)r * 128 + (i & 127)] : 0.0f;
    }
    __syncthreads();
    const int col   = tid & 127;
    const int rbase = (tid >> 7) * 8;   // 0 or 8
    float acc[8];
#pragma unroll
    for (int r = 0; r < 8; ++r) acc[r] = 0.0f;
#pragma unroll 4
    for (int k = 0; k < 128; ++k) {
        float w = W[k * 128 + col];     // coalesced; W is 64 KB -> L1/L2 resident
#pragma unroll
        for (int r = 0; r < 8; ++r)
            acc[r] += xs[(rbase + r) * 128 + k] * w;   // LDS broadcast, conflict-free
    }
#pragma unroll
    for (int r = 0; r < 8; ++r) {
        int rr = row0 + rbase + r;
        if (rr < N) h[(size_t)rr * 128 + col] = acc[r];
    }
}

// -------- K2: per-node attention logits a_src[n,h], a_dst[n,h] --------
__global__ __launch_bounds__(256) void attn_vec(const float* __restrict__ h,
                                                const float* __restrict__ att_src,
                                                const float* __restrict__ att_dst,
                                                float* __restrict__ a_src,
                                                float* __restrict__ a_dst, int N) {
    int i = blockIdx.x * 256 + threadIdx.x;   // i = n*4 + head
    if (i >= N * 4) return;
    int n  = i >> 2;
    int hd = i & 3;
    const float* hp = h + (size_t)n * 128 + hd * 32;
    const float* as = att_src + hd * 32;
    const float* ad = att_dst + hd * 32;
    float s1 = 0.0f, s2 = 0.0f;
#pragma unroll
    for (int c = 0; c < 32; ++c) {
        float v = hp[c];
        s1 += v * as[c];
        s2 += v * ad[c];
    }
    a_src[i] = s1;
    a_dst[i] = s2;
}

// -------- K3: out[n, c] = bias[c] (accumulation base) --------
__global__ __launch_bounds__(256) void init_out(float* __restrict__ out,
                                                const float* __restrict__ bias,
                                                int total) {
    int i = blockIdx.x * 256 + threadIdx.x;
    if (i < total) out[i] = bias[i & 127];
}

// -------- K4: softmax denominators s[dst,h] += exp(leakyrelu(e)) --------
// (max-subtraction skipped: cancels algebraically, |e| small enough for fp32 exp)
__global__ __launch_bounds__(256) void edge_sum(const int* __restrict__ ei,
                                                const float* __restrict__ a_src,
                                                const float* __restrict__ a_dst,
                                                float* __restrict__ s, int E, int N) {
    int e = blockIdx.x * 256 + threadIdx.x;
    int tot = E + N;
    if (e >= tot) return;
    int src, dst;
    if (e < E) { src = ei[e]; dst = ei[E + e]; }
    else       { src = dst = e - E; }            // self loops
#pragma unroll
    for (int hd = 0; hd < 4; ++hd) {
        float sc = a_src[src * 4 + hd] + a_dst[dst * 4 + hd];
        sc = (sc >= 0.0f) ? sc : NEG_SLOPE * sc;
        atomicAdd(&s[dst * 4 + hd], expf(sc));
    }
}

// -------- K5: out[dst] += alpha * h[src]  (32 threads per edge) --------
__global__ __launch_bounds__(256) void edge_aggr(const int* __restrict__ ei,
                                                 const float* __restrict__ a_src,
                                                 const float* __restrict__ a_dst,
                                                 const float* __restrict__ s,
                                                 const float* __restrict__ h,
                                                 float* __restrict__ out, int E, int N) {
    int t = blockIdx.x * 256 + threadIdx.x;
    int e = t >> 5;        // 32 lanes per edge
    int c = t & 31;
    int tot = E + N;
    if (e >= tot) return;
    int src, dst;
    if (e < E) { src = ei[e]; dst = ei[E + e]; }
    else       { src = dst = e - E; }
#pragma unroll
    for (int hd = 0; hd < 4; ++hd) {
        float sc = a_src[src * 4 + hd] + a_dst[dst * 4 + hd];
        sc = (sc >= 0.0f) ? sc : NEG_SLOPE * sc;
        float alpha = expf(sc) / (s[dst * 4 + hd] + EPS);
        float v = h[(size_t)src * 128 + hd * 32 + c] * alpha;
        atomicAdd(&out[(size_t)dst * 128 + hd * 32 + c], v);
    }
}

extern "C" void kernel_launch(void* const* d_in, const int* in_sizes, int n_in,
                              void* d_out, int out_size, void* d_ws, size_t ws_size,
                              hipStream_t stream) {
    const float* x       = (const float*)d_in[0];
    const int*   ei      = (const int*)  d_in[1];
    const float* W       = (const float*)d_in[2];
    const float* att_src = (const float*)d_in[3];
    const float* att_dst = (const float*)d_in[4];
    const float* bias    = (const float*)d_in[5];
    float*       out     = (float*)d_out;

    const int N = in_sizes[0] / 128;
    const int E = in_sizes[1] / 2;

    // workspace layout
    float* h     = (float*)d_ws;                      // N*128
    float* a_src = h     + (size_t)N * 128;           // N*4
    float* a_dst = a_src + (size_t)N * 4;             // N*4
    float* s     = a_dst + (size_t)N * 4;             // N*4

    hipMemsetAsync(s, 0, (size_t)N * 4 * sizeof(float), stream);

    gemm_xw<<<(N + 15) / 16, 256, 0, stream>>>(x, W, h, N);

    attn_vec<<<(N * 4 + 255) / 256, 256, 0, stream>>>(h, att_src, att_dst, a_src, a_dst, N);

    init_out<<<(N * 128 + 255) / 256, 256, 0, stream>>>(out, bias, N * 128);

    edge_sum<<<(E + N + 255) / 256, 256, 0, stream>>>(ei, a_src, a_dst, s, E, N);

    long long tot_threads = (long long)(E + N) * 32;
    edge_aggr<<<(int)((tot_threads + 255) / 256), 256, 0, stream>>>(ei, a_src, a_dst, s, h, out, E, N);
}

// Round 2
// 619.647 us; speedup vs baseline: 1.9467x; 1.9467x over previous
//
#include <hip/hip_runtime.h>

#define NEG_SLOPE 0.2f
#define EPS 1e-16f

// -------- K1: h = x @ W   (N x 128)(128 x 128) fp32, vector ALU --------
// 32 rows x 128 cols per block; each of 256 threads computes a 4x4 tile.
// x tile staged in LDS with +1 padding (conflict-free scalar reads);
// W read as float4 from global (64 KB, L1/L2 resident, shared across blocks).
__global__ __launch_bounds__(256) void gemm_xw(const float* __restrict__ x,
                                               const float* __restrict__ W,
                                               float* __restrict__ h, int N) {
    __shared__ float xs[32][129];   // 16.5 KB; pad 129 => bank(r*129+k) distinct over r
    const int tid  = threadIdx.x;
    const int row0 = blockIdx.x * 32;
    // stage x tile: 4096 floats, 16/thread, float4 coalesced
    for (int i = tid * 4; i < 32 * 128; i += 256 * 4) {
        int r = i >> 7, cc = i & 127;
        float4 v = make_float4(0.f, 0.f, 0.f, 0.f);
        if (row0 + r < N) v = *(const float4*)(x + (size_t)(row0 + r) * 128 + cc);
        xs[r][cc] = v.x; xs[r][cc + 1] = v.y; xs[r][cc + 2] = v.z; xs[r][cc + 3] = v.w;
    }
    __syncthreads();
    const int c0 = (tid & 31) * 4;
    const int r0 = (tid >> 5) * 4;
    float acc[4][4];
#pragma unroll
    for (int i = 0; i < 4; ++i)
#pragma unroll
        for (int j = 0; j < 4; ++j) acc[i][j] = 0.f;
#pragma unroll 2
    for (int k = 0; k < 128; ++k) {
        float4 b = *(const float4*)(W + k * 128 + c0);
        float a0 = xs[r0][k], a1 = xs[r0 + 1][k], a2 = xs[r0 + 2][k], a3 = xs[r0 + 3][k];
        acc[0][0] = fmaf(a0, b.x, acc[0][0]); acc[0][1] = fmaf(a0, b.y, acc[0][1]);
        acc[0][2] = fmaf(a0, b.z, acc[0][2]); acc[0][3] = fmaf(a0, b.w, acc[0][3]);
        acc[1][0] = fmaf(a1, b.x, acc[1][0]); acc[1][1] = fmaf(a1, b.y, acc[1][1]);
        acc[1][2] = fmaf(a1, b.z, acc[1][2]); acc[1][3] = fmaf(a1, b.w, acc[1][3]);
        acc[2][0] = fmaf(a2, b.x, acc[2][0]); acc[2][1] = fmaf(a2, b.y, acc[2][1]);
        acc[2][2] = fmaf(a2, b.z, acc[2][2]); acc[2][3] = fmaf(a2, b.w, acc[2][3]);
        acc[3][0] = fmaf(a3, b.x, acc[3][0]); acc[3][1] = fmaf(a3, b.y, acc[3][1]);
        acc[3][2] = fmaf(a3, b.z, acc[3][2]); acc[3][3] = fmaf(a3, b.w, acc[3][3]);
    }
#pragma unroll
    for (int i = 0; i < 4; ++i) {
        int rr = row0 + r0 + i;
        if (rr < N)
            *(float4*)(h + (size_t)rr * 128 + c0) =
                make_float4(acc[i][0], acc[i][1], acc[i][2], acc[i][3]);
    }
}

// -------- K2: per-node attention logits --------
__global__ __launch_bounds__(256) void attn_vec(const float* __restrict__ h,
                                                const float* __restrict__ att_src,
                                                const float* __restrict__ att_dst,
                                                float* __restrict__ a_src,
                                                float* __restrict__ a_dst, int N) {
    int i = blockIdx.x * 256 + threadIdx.x;   // i = n*4 + head
    if (i >= N * 4) return;
    int n  = i >> 2;
    int hd = i & 3;
    const float* hp = h + (size_t)n * 128 + hd * 32;
    const float* as = att_src + hd * 32;
    const float* ad = att_dst + hd * 32;
    float s1 = 0.0f, s2 = 0.0f;
#pragma unroll
    for (int c = 0; c < 32; ++c) {
        float v = hp[c];
        s1 = fmaf(v, as[c], s1);
        s2 = fmaf(v, ad[c], s2);
    }
    a_src[i] = s1;
    a_dst[i] = s2;
}

// -------- K3: in-degree histogram --------
__global__ __launch_bounds__(256) void hist(const int* __restrict__ ei,
                                            int* __restrict__ counts, int E, int N) {
    int e = blockIdx.x * 256 + threadIdx.x;
    int T = E + N;
    if (e >= T) return;
    int dst = (e < E) ? ei[E + e] : (e - E);
    atomicAdd(&counts[dst], 1);
}

// -------- K4a: per-block exclusive scan of counts --------
__global__ __launch_bounds__(256) void scan1(const int* __restrict__ counts,
                                             int* __restrict__ offs,
                                             int* __restrict__ bsums, int N) {
    __shared__ int sh[256];
    int i = blockIdx.x * 256 + threadIdx.x;
    int v = (i < N) ? counts[i] : 0;
    sh[threadIdx.x] = v;
    __syncthreads();
    for (int off = 1; off < 256; off <<= 1) {
        int y = (threadIdx.x >= (unsigned)off) ? sh[threadIdx.x - off] : 0;
        __syncthreads();
        sh[threadIdx.x] += y;
        __syncthreads();
    }
    if (i < N) offs[i] = sh[threadIdx.x] - v;   // exclusive
    if (threadIdx.x == 255) bsums[blockIdx.x] = sh[255];
}

// -------- K4b: scan of block sums (single block, up to 512 blocks) --------
__global__ __launch_bounds__(512) void scan2(int* __restrict__ bsums, int nb) {
    __shared__ int sh[512];
    int t = threadIdx.x;
    int v = (t < nb) ? bsums[t] : 0;
    sh[t] = v;
    __syncthreads();
    for (int off = 1; off < 512; off <<= 1) {
        int y = (t >= off) ? sh[t - off] : 0;
        __syncthreads();
        sh[t] += y;
        __syncthreads();
    }
    bsums[t] = sh[t] - v;   // exclusive
}

// -------- K4c: add block offsets; init cursors --------
__global__ __launch_bounds__(256) void scan3(int* __restrict__ offs,
                                             const int* __restrict__ bsums,
                                             int* __restrict__ cursor, int N) {
    int i = blockIdx.x * 256 + threadIdx.x;
    if (i < N) {
        int o = offs[i] + bsums[i >> 8];
        offs[i]   = o;
        cursor[i] = o;
    }
}

// -------- K5: scatter edges into dst-grouped CSR --------
__global__ __launch_bounds__(256) void scatter(const int* __restrict__ ei,
                                               int* __restrict__ cursor,
                                               int* __restrict__ csr, int E, int N) {
    int e = blockIdx.x * 256 + threadIdx.x;
    int T = E + N;
    if (e >= T) return;
    int src, dst;
    if (e < E) { src = ei[e]; dst = ei[E + e]; }
    else       { src = dst = e - E; }
    int pos = atomicAdd(&cursor[dst], 1);
    csr[pos] = src;
}

// -------- K6: per-node single-pass softmax-aggregate, no atomics --------
// 128 threads per node (one per output channel); un-normalized accumulation,
// divide by the exp-sum at the end. Max-subtraction cancels algebraically and
// |score| is small enough that exp() cannot overflow fp32.
__global__ __launch_bounds__(256) void aggr_csr(const int* __restrict__ csr,
                                                const int* __restrict__ offs,
                                                const int* __restrict__ counts,
                                                const float* __restrict__ a_src,
                                                const float* __restrict__ a_dst,
                                                const float* __restrict__ h,
                                                const float* __restrict__ bias,
                                                float* __restrict__ out, int N) {
    int node = blockIdx.x * 2 + (threadIdx.x >> 7);
    if (node >= N) return;
    int c  = threadIdx.x & 127;
    int hd = c >> 5;
    float ad  = a_dst[node * 4 + hd];
    int beg = offs[node];
    int cnt = counts[node];          // >= 1 (self loop)
    float acc = 0.f, den = 0.f;
    int src_next = csr[beg];
    for (int k = 0; k < cnt; ++k) {
        int src = src_next;
        if (k + 1 < cnt) src_next = csr[beg + k + 1];   // prefetch next index
        float sc = a_src[src * 4 + hd] + ad;
        sc = (sc >= 0.f) ? sc : NEG_SLOPE * sc;
        float ex = __expf(sc);
        den += ex;
        acc = fmaf(ex, h[(size_t)src * 128 + c], acc);
    }
    out[(size_t)node * 128 + c] = acc / (den + EPS) + bias[c];
}

extern "C" void kernel_launch(void* const* d_in, const int* in_sizes, int n_in,
                              void* d_out, int out_size, void* d_ws, size_t ws_size,
                              hipStream_t stream) {
    const float* x       = (const float*)d_in[0];
    const int*   ei      = (const int*)  d_in[1];
    const float* W       = (const float*)d_in[2];
    const float* att_src = (const float*)d_in[3];
    const float* att_dst = (const float*)d_in[4];
    const float* bias    = (const float*)d_in[5];
    float*       out     = (float*)d_out;

    const int N = in_sizes[0] / 128;
    const int E = in_sizes[1] / 2;
    const int T = E + N;

    // workspace layout
    float* h      = (float*)d_ws;                  // N*128
    float* a_src  = h     + (size_t)N * 128;       // N*4
    float* a_dst  = a_src + (size_t)N * 4;         // N*4
    int*   counts = (int*)(a_dst + (size_t)N * 4); // N
    int*   offs   = counts + N;                    // N
    int*   cursor = offs   + N;                    // N
    int*   bsums  = cursor + N;                    // 512
    int*   csr    = bsums  + 512;                  // T

    const int nb = (N + 255) / 256;

    hipMemsetAsync(counts, 0, (size_t)N * sizeof(int), stream);

    gemm_xw<<<(N + 31) / 32, 256, 0, stream>>>(x, W, h, N);
    attn_vec<<<(N * 4 + 255) / 256, 256, 0, stream>>>(h, att_src, att_dst, a_src, a_dst, N);

    hist<<<(T + 255) / 256, 256, 0, stream>>>(ei, counts, E, N);
    scan1<<<nb, 256, 0, stream>>>(counts, offs, bsums, N);
    scan2<<<1, 512, 0, stream>>>(bsums, nb);
    scan3<<<nb, 256, 0, stream>>>(offs, bsums, cursor, N);
    scatter<<<(T + 255) / 256, 256, 0, stream>>>(ei, cursor, csr, E, N);

    aggr_csr<<<(N + 1) / 2, 256, 0, stream>>>(csr, offs, counts, a_src, a_dst, h, bias, out, N);
}

// Round 3
// 421.894 us; speedup vs baseline: 2.8592x; 1.4687x over previous
//
#include <hip/hip_runtime.h>
#include <hip/hip_fp16.h>

#define NEG_SLOPE 0.2f
#define EPS 1e-16f

// -------- K1: h16 = fp16(x @ W), fused per-node logits a_src/a_dst --------
// 32 rows x 128 cols per block, 4x4 register tile per thread.
// Logits: dot(h[n,hd,:], att[hd,:]) reduced across the 8 lanes that own a head.
__global__ __launch_bounds__(256) void gemm_fused(const float* __restrict__ x,
                                                  const float* __restrict__ W,
                                                  const float* __restrict__ att_src,
                                                  const float* __restrict__ att_dst,
                                                  __half* __restrict__ h16,
                                                  float* __restrict__ a_src,
                                                  float* __restrict__ a_dst, int N) {
    __shared__ float xs[32][129];   // +1 pad: conflict-free
    const int tid  = threadIdx.x;
    const int row0 = blockIdx.x * 32;
    for (int i = tid * 4; i < 32 * 128; i += 256 * 4) {
        int r = i >> 7, cc = i & 127;
        float4 v = make_float4(0.f, 0.f, 0.f, 0.f);
        if (row0 + r < N) v = *(const float4*)(x + (size_t)(row0 + r) * 128 + cc);
        xs[r][cc] = v.x; xs[r][cc + 1] = v.y; xs[r][cc + 2] = v.z; xs[r][cc + 3] = v.w;
    }
    __syncthreads();
    const int c0 = (tid & 31) * 4;        // global channel of first col
    const int r0 = (tid >> 5) * 4;
    float acc[4][4];
#pragma unroll
    for (int i = 0; i < 4; ++i)
#pragma unroll
        for (int j = 0; j < 4; ++j) acc[i][j] = 0.f;
#pragma unroll 2
    for (int k = 0; k < 128; ++k) {
        float4 b = *(const float4*)(W + k * 128 + c0);
        float a0 = xs[r0][k], a1 = xs[r0 + 1][k], a2 = xs[r0 + 2][k], a3 = xs[r0 + 3][k];
        acc[0][0] = fmaf(a0, b.x, acc[0][0]); acc[0][1] = fmaf(a0, b.y, acc[0][1]);
        acc[0][2] = fmaf(a0, b.z, acc[0][2]); acc[0][3] = fmaf(a0, b.w, acc[0][3]);
        acc[1][0] = fmaf(a1, b.x, acc[1][0]); acc[1][1] = fmaf(a1, b.y, acc[1][1]);
        acc[1][2] = fmaf(a1, b.z, acc[1][2]); acc[1][3] = fmaf(a1, b.w, acc[1][3]);
        acc[2][0] = fmaf(a2, b.x, acc[2][0]); acc[2][1] = fmaf(a2, b.y, acc[2][1]);
        acc[2][2] = fmaf(a2, b.z, acc[2][2]); acc[2][3] = fmaf(a2, b.w, acc[2][3]);
        acc[3][0] = fmaf(a3, b.x, acc[3][0]); acc[3][1] = fmaf(a3, b.y, acc[3][1]);
        acc[3][2] = fmaf(a3, b.z, acc[3][2]); acc[3][3] = fmaf(a3, b.w, acc[3][3]);
    }
    // epilogue: h16 store + fused logits
    const int hd = (tid & 31) >> 3;       // head owned by this lane group of 8
    float s0 = att_src[c0], s1 = att_src[c0 + 1], s2 = att_src[c0 + 2], s3 = att_src[c0 + 3];
    float d0 = att_dst[c0], d1 = att_dst[c0 + 1], d2 = att_dst[c0 + 2], d3 = att_dst[c0 + 3];
#pragma unroll
    for (int i = 0; i < 4; ++i) {
        int rr = row0 + r0 + i;
        float ps = fmaf(acc[i][0], s0, fmaf(acc[i][1], s1, fmaf(acc[i][2], s2, acc[i][3] * s3)));
        float pd = fmaf(acc[i][0], d0, fmaf(acc[i][1], d1, fmaf(acc[i][2], d2, acc[i][3] * d3)));
        // reduce over the 8 lanes (tid bits 0..2 vary c0 by 4/8/16 within the head)
        ps += __shfl_xor(ps, 1); ps += __shfl_xor(ps, 2); ps += __shfl_xor(ps, 4);
        pd += __shfl_xor(pd, 1); pd += __shfl_xor(pd, 2); pd += __shfl_xor(pd, 4);
        if (rr < N) {
            __half2 lo = __floats2half2_rn(acc[i][0], acc[i][1]);
            __half2 hi = __floats2half2_rn(acc[i][2], acc[i][3]);
            __half2* hp = (__half2*)(h16 + (size_t)rr * 128 + c0);
            hp[0] = lo; hp[1] = hi;
            if ((tid & 7) == 0) { a_src[rr * 4 + hd] = ps; a_dst[rr * 4 + hd] = pd; }
        }
    }
}

// -------- K2: in-degree histogram --------
__global__ __launch_bounds__(256) void hist(const int* __restrict__ ei,
                                            int* __restrict__ counts, int E, int N) {
    int e = blockIdx.x * 256 + threadIdx.x;
    int T = E + N;
    if (e >= T) return;
    int dst = (e < E) ? ei[E + e] : (e - E);
    atomicAdd(&counts[dst], 1);
}

// -------- K3a: per-block exclusive scan of counts --------
__global__ __launch_bounds__(256) void scan1(const int* __restrict__ counts,
                                             int* __restrict__ offs,
                                             int* __restrict__ bsums, int N) {
    __shared__ int sh[256];
    int i = blockIdx.x * 256 + threadIdx.x;
    int v = (i < N) ? counts[i] : 0;
    sh[threadIdx.x] = v;
    __syncthreads();
    for (int off = 1; off < 256; off <<= 1) {
        int y = (threadIdx.x >= (unsigned)off) ? sh[threadIdx.x - off] : 0;
        __syncthreads();
        sh[threadIdx.x] += y;
        __syncthreads();
    }
    if (i < N) offs[i] = sh[threadIdx.x] - v;
    if (threadIdx.x == 255) bsums[blockIdx.x] = sh[255];
}

// -------- K3b: scan of block sums --------
__global__ __launch_bounds__(512) void scan2(int* __restrict__ bsums, int nb) {
    __shared__ int sh[512];
    int t = threadIdx.x;
    int v = (t < nb) ? bsums[t] : 0;
    sh[t] = v;
    __syncthreads();
    for (int off = 1; off < 512; off <<= 1) {
        int y = (t >= off) ? sh[t - off] : 0;
        __syncthreads();
        sh[t] += y;
        __syncthreads();
    }
    bsums[t] = sh[t] - v;
}

// -------- K3c: add block offsets; init cursors --------
__global__ __launch_bounds__(256) void scan3(int* __restrict__ offs,
                                             const int* __restrict__ bsums,
                                             int* __restrict__ cursor, int N) {
    int i = blockIdx.x * 256 + threadIdx.x;
    if (i < N) {
        int o = offs[i] + bsums[i >> 8];
        offs[i]   = o;
        cursor[i] = o;
    }
}

// -------- K4: scatter edges into dst-grouped CSR + precompute exp weights --------
__global__ __launch_bounds__(256) void scatter(const int* __restrict__ ei,
                                               const float* __restrict__ a_src,
                                               const float* __restrict__ a_dst,
                                               int* __restrict__ cursor,
                                               int* __restrict__ csr,
                                               float4* __restrict__ wexp,
                                               int E, int N) {
    int e = blockIdx.x * 256 + threadIdx.x;
    int T = E + N;
    if (e >= T) return;
    int src, dst;
    if (e < E) { src = ei[e]; dst = ei[E + e]; }
    else       { src = dst = e - E; }
    int pos = atomicAdd(&cursor[dst], 1);
    csr[pos] = src;
    float4 as = *(const float4*)(a_src + src * 4);
    float4 ad = *(const float4*)(a_dst + dst * 4);
    float4 w;
    float sc;
    sc = as.x + ad.x; sc = (sc >= 0.f) ? sc : NEG_SLOPE * sc; w.x = __expf(sc);
    sc = as.y + ad.y; sc = (sc >= 0.f) ? sc : NEG_SLOPE * sc; w.y = __expf(sc);
    sc = as.z + ad.z; sc = (sc >= 0.f) ? sc : NEG_SLOPE * sc; w.z = __expf(sc);
    sc = as.w + ad.w; sc = (sc >= 0.f) ? sc : NEG_SLOPE * sc; w.w = __expf(sc);
    wexp[pos] = w;
}

// -------- K5: per-node aggregate: 64 lanes/node, half2 gathers, unroll-4 --------
__global__ __launch_bounds__(256) void aggr_csr(const int* __restrict__ csr,
                                                const float* __restrict__ wexp,
                                                const int* __restrict__ offs,
                                                const int* __restrict__ counts,
                                                const __half2* __restrict__ h16,
                                                const float* __restrict__ bias,
                                                float* __restrict__ out, int N) {
    int node = blockIdx.x * 4 + (threadIdx.x >> 6);
    if (node >= N) return;
    int lane = threadIdx.x & 63;
    int hd   = lane >> 4;          // 16 lanes (32 channels) per head
    int beg  = offs[node];
    int cnt  = counts[node];       // >= 1 (self loop)
    float ax = 0.f, ay = 0.f, den = 0.f;
    int k = 0;
    for (; k + 4 <= cnt; k += 4) {
        int b = beg + k;
        int s0 = csr[b], s1 = csr[b + 1], s2 = csr[b + 2], s3 = csr[b + 3];
        float w0 = wexp[(size_t)b * 4 + hd];
        float w1 = wexp[(size_t)(b + 1) * 4 + hd];
        float w2 = wexp[(size_t)(b + 2) * 4 + hd];
        float w3 = wexp[(size_t)(b + 3) * 4 + hd];
        __half2 g0 = h16[(size_t)s0 * 64 + lane];
        __half2 g1 = h16[(size_t)s1 * 64 + lane];
        __half2 g2 = h16[(size_t)s2 * 64 + lane];
        __half2 g3 = h16[(size_t)s3 * 64 + lane];
        float2 f0 = __half22float2(g0), f1 = __half22float2(g1);
        float2 f2 = __half22float2(g2), f3 = __half22float2(g3);
        ax = fmaf(w0, f0.x, ax); ay = fmaf(w0, f0.y, ay);
        ax = fmaf(w1, f1.x, ax); ay = fmaf(w1, f1.y, ay);
        ax = fmaf(w2, f2.x, ax); ay = fmaf(w2, f2.y, ay);
        ax = fmaf(w3, f3.x, ax); ay = fmaf(w3, f3.y, ay);
        den += w0 + w1 + w2 + w3;
    }
    for (; k < cnt; ++k) {
        int b = beg + k;
        int s = csr[b];
        float w = wexp[(size_t)b * 4 + hd];
        float2 f = __half22float2(h16[(size_t)s * 64 + lane]);
        ax = fmaf(w, f.x, ax); ay = fmaf(w, f.y, ay);
        den += w;
    }
    float inv = 1.f / (den + EPS);
    int c = lane * 2;
    float2 o;
    o.x = fmaf(ax, inv, bias[c]);
    o.y = fmaf(ay, inv, bias[c + 1]);
    *(float2*)(out + (size_t)node * 128 + c) = o;
}

extern "C" void kernel_launch(void* const* d_in, const int* in_sizes, int n_in,
                              void* d_out, int out_size, void* d_ws, size_t ws_size,
                              hipStream_t stream) {
    const float* x       = (const float*)d_in[0];
    const int*   ei      = (const int*)  d_in[1];
    const float* W       = (const float*)d_in[2];
    const float* att_src = (const float*)d_in[3];
    const float* att_dst = (const float*)d_in[4];
    const float* bias    = (const float*)d_in[5];
    float*       out     = (float*)d_out;

    const int N = in_sizes[0] / 128;
    const int E = in_sizes[1] / 2;
    const int T = E + N;

    // workspace layout
    __half* h16   = (__half*)d_ws;                        // N*128 halfs
    float*  a_src = (float*)(h16 + (size_t)N * 128);      // N*4
    float*  a_dst = a_src + (size_t)N * 4;                // N*4
    int*    counts = (int*)(a_dst + (size_t)N * 4);       // N
    int*    offs   = counts + N;                          // N
    int*    cursor = offs + N;                            // N
    int*    bsums  = cursor + N;                          // 512
    int*    csr    = bsums + 512;                         // T
    float4* wexp   = (float4*)(csr + ((T + 3) & ~3));     // T float4 (16B aligned)

    const int nb = (N + 255) / 256;

    hipMemsetAsync(counts, 0, (size_t)N * sizeof(int), stream);

    gemm_fused<<<(N + 31) / 32, 256, 0, stream>>>(x, W, att_src, att_dst, h16, a_src, a_dst, N);

    hist<<<(T + 255) / 256, 256, 0, stream>>>(ei, counts, E, N);
    scan1<<<nb, 256, 0, stream>>>(counts, offs, bsums, N);
    scan2<<<1, 512, 0, stream>>>(bsums, nb);
    scan3<<<nb, 256, 0, stream>>>(offs, bsums, cursor, N);
    scatter<<<(T + 255) / 256, 256, 0, stream>>>(ei, a_src, a_dst, cursor, csr, wexp, E, N);

    aggr_csr<<<(N + 3) / 4, 256, 0, stream>>>(csr, (const float*)wexp, offs, counts,
                                              (const __half2*)h16, bias, out, N);
}